// Round 1
// 96.539 us; speedup vs baseline: 1.0730x; 1.0730x over previous
//
#include <hip/hip_runtime.h>
#include <stdint.h>

// Fused dynamic-filter network op, bf16 MFMA implicit-GEMM, pipelined.
//   filt[n,oc,h,w] = bc[oc] + sum_{ic,kh,kw} gt_zpad[n,ic,h+kh-1,w+kw-1]*Wc[oc,ic,kh,kw]
//   out[n,c,h,w]   = sum_{k=kh*3+kw} filt[n,c*9+k,h,w] * gr_reppad[n,c,h+kh-1,w+kw-1]
// N=8, C=64, H=W=128, OC=576. filt (302 MB) never materialized.
//
// ws layout:
//   [0, 663552)          Wc bf16, 36 blocks of [144 oc][64 ic], XOR-swizzled,
//                        oc rows PERMUTED: tile row r holds oc (r&15)*9 + (r>>4)
//   [663552, 680192)     16640 B of zeros (OOB row source for conv zero-pad in h)
//   [680192, 17719552)   gt bf16 row-blocks [n][y]: [130 r=w+1][64 ic], swizzled,
//                        r=0 and r=129 are zero rows (conv zero-pad in w)
//
// R10 vs R9: register-direct epilogue via operand swap + oc permutation.
//  - MFMA computes D = Wc * patches (swapped args): C col = lane&15 = pixel,
//    row = l4*4+reg. With the pi permutation on Wc rows, acc[mf][k][q] holds
//    filt for pixel (mf,l15), channel l4*4+q, dyn-tap k — the 9 taps of one
//    output are SAME-LANE, SAME-REG-SLICE.
//  - Epilogue LDS round-trip (144 ds_write_b16 + 32 reads + 2 lgkm waits per
//    mf per wave) deleted; no filt bf16 rounding; final barrier deleted
//    (epilogue touches no LDS). 5 barriers total (was 6).

typedef short bf16x8 __attribute__((ext_vector_type(8)));
typedef float f32x4 __attribute__((ext_vector_type(4)));

#define ROWBLK_B 16640
#define BTAP_B   18432
#define ZERO_OFF 663552
#define GTB_OFF  (ZERO_OFF + ROWBLK_B)

__device__ __forceinline__ uint32_t f2bf(float f) {
  uint32_t x = __float_as_uint(f);
  return (x + 0x7FFFu + ((x >> 16) & 1u)) >> 16;   // RNE
}

__device__ __forceinline__ void gload_lds16(const void* g, void* l) {
  __builtin_amdgcn_global_load_lds(
      (const __attribute__((address_space(1))) void*)g,
      (__attribute__((address_space(3))) void*)l, 16, 0, 0);
}

// ---- prep 1: Wc [576][64][3][3] f32 -> ws bf16 [tap*4+octile][144][64], pre-swizzled.
// Tile row r holds original oc = octile*144 + (r&15)*9 + (r>>4)  (pi permutation:
// D-row nf*16 + l4*4+q  ->  channel l4*4+q, dyn-tap nf).
__global__ void prep_wc(const float* __restrict__ Wc, uint8_t* __restrict__ ws) {
  int ch = blockIdx.x * 256 + threadIdx.x;   // 41472 x 16B chunks, exact
  int tb = ch / 1152;                        // tap*4 + octile
  int cw = ch - tb * 1152;
  int tap = tb >> 2, octile = tb & 3;
  int row = cw >> 3, sl = cw & 7;
  int slot = sl ^ (row & 7);                 // pre-apply read-side XOR swizzle
  int ic0 = slot * 8;
  int oc = octile * 144 + (row & 15) * 9 + (row >> 4);   // pi permutation
  uint32_t p[4];
#pragma unroll
  for (int e = 0; e < 4; ++e) {
    uint32_t lo = f2bf(Wc[(oc * 64 + ic0 + 2 * e) * 9 + tap]);
    uint32_t hi = f2bf(Wc[(oc * 64 + ic0 + 2 * e + 1) * 9 + tap]);
    p[e] = lo | (hi << 16);
  }
  uint4 u; u.x = p[0]; u.y = p[1]; u.z = p[2]; u.w = p[3];
  *(uint4*)(ws + (size_t)tb * BTAP_B + (size_t)cw * 16) = u;
}

// ---- prep 2: gt [8][64][128][128] f32 -> ws bf16 row-blocks, pre-swizzled, padded
__global__ void prep_gt(const float* __restrict__ gt, uint8_t* __restrict__ ws) {
  int b = blockIdx.x;
  if (b == 1024) {  // zero block for out-of-image rows
    uint4 z; z.x = z.y = z.z = z.w = 0;
    for (int i = threadIdx.x; i < 1040; i += 256)
      *(uint4*)(ws + ZERO_OFF + (size_t)i * 16) = z;
    return;
  }
  int n = b >> 7, y = b & 127;
  uint8_t* base = ws + GTB_OFF + (size_t)b * ROWBLK_B;
  for (int i = threadIdx.x; i < 1040; i += 256) {   // 1040 x 16B chunks per row-block
    int r = i >> 3, sl = i & 7;
    int slot = sl ^ (r & 7);
    uint4 u; u.x = u.y = u.z = u.w = 0;
    if (r >= 1 && r <= 128) {
      int w = r - 1, ic0 = slot * 8;
      uint32_t p[4];
#pragma unroll
      for (int e = 0; e < 4; ++e) {
        uint32_t lo = f2bf(gt[((n * 64 + ic0 + 2 * e) * 128 + y) * 128 + w]);
        uint32_t hi = f2bf(gt[((n * 64 + ic0 + 2 * e + 1) * 128 + y) * 128 + w]);
        p[e] = lo | (hi << 16);
      }
      u.x = p[0]; u.y = p[1]; u.z = p[2]; u.w = p[3];
    }
    *(uint4*)(base + (size_t)i * 16) = u;
  }
}

// ---- main: per block M=512 pixels (4 rows x 128 w) x N=144 oc, K=576
__global__ __launch_bounds__(512, 2) void dfn_mfma(
    const float* __restrict__ gr, const float* __restrict__ bc,
    const uint8_t* __restrict__ ws, float* __restrict__ out) {
  __shared__ uint8_t smem[156928];           // A 5x16640=83200 + B 4x18432=73728
  uint8_t* Abuf = smem;
  uint8_t* Bbuf = smem + 83200;
  const int tid = threadIdx.x;
  const int lane = tid & 63;
  const int wv = tid >> 6;
  const int l15 = lane & 15;
  const int l4 = lane >> 4;
  // XCD-coscheduling decode: bits[2:0]=nh_low, bits[4:3]=octile, bits[9:5]=nh_high.
  const int bid = blockIdx.x;
  const int octile = (bid >> 3) & 3;
  const int nh = (bid & 7) | ((bid >> 5) << 3);
  const int n = nh >> 5;
  const int h0 = (nh & 31) * 4;

  // ---- precomputed per-lane ds_read offsets (swizzle algebra, zero inner VALU)
  int bo[2], aoff[3][2];
#pragma unroll
  for (int kk = 0; kk < 2; ++kk) {
    bo[kk] = l15 * 128 + ((kk * 64 + l4 * 16) ^ ((l15 & 7) << 4));
#pragma unroll
    for (int dwp = 0; dwp < 3; ++dwp) {
      int rl = l15 + dwp;
      aoff[dwp][kk] = rl * 128 + ((kk * 64 + l4 * 16) ^ ((rl & 7) << 4));
    }
  }
  int mrow[4], mcol[4];
#pragma unroll
  for (int mf = 0; mf < 4; ++mf) {
    mrow[mf] = (wv * 4 + mf) >> 3;           // image-row index within block tile
    mcol[mf] = ((wv * 4 + mf) & 7) * 2048;   // wbase*128
  }

  const uint8_t* gtb = ws + GTB_OFF;
  const uint8_t* zblk = ws + ZERO_OFF;

#define ISSUE_B(T, BUFI) do {                                                 \
    const uint8_t* bsrc_ = ws + (size_t)((T) * 4 + octile) * BTAP_B;          \
    uint8_t* bdst_ = Bbuf + (BUFI) * BTAP_B;                                  \
    _Pragma("unroll")                                                         \
    for (int it = 0; it < 3; ++it) {                                          \
      int idx = it * 512 + tid;                                               \
      if (idx < 1152)                                                         \
        gload_lds16(bsrc_ + (size_t)idx * 16,                                 \
                    bdst_ + (size_t)(it * 512 + (tid & ~63)) * 16);           \
    }                                                                         \
  } while (0)

#define ISSUE_AROW(Y, SLOT) do {                                              \
    int y_ = (Y);                                                             \
    const uint8_t* src_ = (y_ >= 0 && y_ < 128)                               \
        ? (gtb + (size_t)(n * 128 + y_) * ROWBLK_B) : zblk;                   \
    uint8_t* dst_ = Abuf + (SLOT) * ROWBLK_B;                                 \
    _Pragma("unroll")                                                         \
    for (int it = 0; it < 3; ++it) {                                          \
      int idx = it * 512 + tid;                                               \
      if (idx < 1040)                                                         \
        gload_lds16(src_ + (size_t)idx * 16,                                  \
                    dst_ + (size_t)(it * 512 + (tid & ~63)) * 16);            \
    }                                                                         \
  } while (0)

// one tap: DH in {-1,0,1}, DWP = dw+1 literal, BUFI = B ring slot
// NOTE operand order: mfma(Wc_frag, pixel_frag, acc) -> C col = pixel,
// row = l4*4+reg = pi-channel slice.
#define TAP(DH, DWP, BUFI) do {                                               \
    const uint8_t* Bcur_ = Bbuf + (BUFI) * BTAP_B;                            \
    _Pragma("unroll")                                                         \
    for (int kk = 0; kk < 2; ++kk) {                                          \
      bf16x8 afr[4];                                                          \
      _Pragma("unroll")                                                       \
      for (int mf = 0; mf < 4; ++mf) {                                        \
        int idx_ = mrow[mf] + ((DH) + 1);      /* 0..5 */                     \
        int slot_ = (idx_ == 5) ? 0 : idx_;    /* row h0+4 lives in slot 0 */ \
        afr[mf] = *(const bf16x8*)(Abuf + slot_ * ROWBLK_B + mcol[mf]         \
                                   + aoff[DWP][kk]);                          \
      }                                                                       \
      const uint8_t* baddr_ = Bcur_ + bo[kk];                                 \
      bf16x8 bq[4];                                                           \
      _Pragma("unroll")                                                       \
      for (int p = 0; p < 4; ++p)                                             \
        bq[p] = *(const bf16x8*)(baddr_ + p * 2048);                          \
      __builtin_amdgcn_s_setprio(1);                                          \
      _Pragma("unroll")                                                       \
      for (int nf = 0; nf < 9; ++nf) {                                        \
        bf16x8 bcur_ = bq[nf & 3];                                            \
        if (nf + 4 < 9)                                                       \
          bq[nf & 3] = *(const bf16x8*)(baddr_ + (nf + 4) * 2048);            \
        _Pragma("unroll")                                                     \
        for (int mf = 0; mf < 4; ++mf)                                        \
          acc[mf][nf] = __builtin_amdgcn_mfma_f32_16x16x32_bf16(              \
              bcur_, afr[mf], acc[mf][nf], 0, 0, 0);                          \
      }                                                                       \
      __builtin_amdgcn_s_setprio(0);                                          \
    }                                                                         \
  } while (0)

  // ---- prologue: A slots 0..4 (rows h0-1 .. h0+3) + B taps 0,1
#pragma unroll
  for (int row = 0; row < 5; ++row) ISSUE_AROW(h0 - 1 + row, row);
  ISSUE_B(0, 0);
  ISSUE_B(1, 1);

  // bias init overlaps the staging loads: acc[mf][nf][q] = bc for
  // oc = octile*144 + (l4*4+q)*9 + nf  (channel l4*4+q, dyn-tap nf)
  f32x4 acc[4][9];
#pragma unroll
  for (int nf = 0; nf < 9; ++nf) {
#pragma unroll
    for (int q = 0; q < 4; ++q) {
      float bias = bc[octile * 144 + (l4 * 4 + q) * 9 + nf];
      acc[0][nf][q] = bias; acc[1][nf][q] = bias;
      acc[2][nf][q] = bias; acc[3][nf][q] = bias;
    }
  }
  __syncthreads();                            // drain: A(5) + B0,B1 visible

  // ---- window 0: taps 0,1; prefetch taps 2,3
  ISSUE_B(2, 2); ISSUE_B(3, 3);
  TAP(-1, 0, 0); TAP(-1, 1, 1);
  __syncthreads();
  // ---- window 1: taps 2,3; prefetch taps 4,5 (buf0,1 freed by barrier)
  ISSUE_B(4, 0); ISSUE_B(5, 1);
  TAP(-1, 2, 2); TAP(0, 0, 3);
  __syncthreads();
  // ---- window 2: taps 4,5; prefetch 6,7 + A row h0+4 -> slot 0
  //      (slot 0's old row h0-1 last read at tap 2; freed by window-1 barrier)
  ISSUE_B(6, 2); ISSUE_B(7, 3);
  ISSUE_AROW(h0 + 4, 0);
  TAP(0, 1, 0); TAP(0, 2, 1);
  __syncthreads();
  // ---- window 3: taps 6,7; prefetch tap 8
  ISSUE_B(8, 0);
  TAP(1, 0, 2); TAP(1, 1, 3);
  __syncthreads();
  // ---- tap 8; no trailing barrier (epilogue touches no LDS)
  TAP(1, 2, 0);

  // ---- epilogue: register-direct. acc[mf][k][q] = filt(pixel(mf,l15),
  // channel l4*4+q, tap k). Pure VALU + global; no LDS, no bf16 rounding.
  const float* grb = gr + (size_t)(n * 64 + octile * 16 + l4 * 4) * 16384;
  float* outb = out + (size_t)(n * 64 + octile * 16 + l4 * 4) * 16384;
#pragma unroll
  for (int mf = 0; mf < 4; ++mf) {
    int p = (wv * 4 + mf) * 16 + l15;         // pixel within 512-pixel tile
    int hrow = p >> 7, w = p & 127;
    int h = h0 + hrow;
    int off[3][3];                            // replicate-clamped, shared over q
#pragma unroll
    for (int i = 0; i < 3; ++i) {
      int yy = h + i - 1; yy = yy < 0 ? 0 : (yy > 127 ? 127 : yy);
#pragma unroll
      for (int j = 0; j < 3; ++j) {
        int xx = w + j - 1; xx = xx < 0 ? 0 : (xx > 127 ? 127 : xx);
        off[i][j] = yy * 128 + xx;
      }
    }
#pragma unroll
    for (int q = 0; q < 4; ++q) {
      const float* grc = grb + (size_t)q * 16384;
      float s = 0.f;
#pragma unroll
      for (int i = 0; i < 3; ++i)
#pragma unroll
        for (int j = 0; j < 3; ++j)
          s = fmaf(acc[mf][i * 3 + j][q], grc[off[i][j]], s);
      outb[(size_t)q * 16384 + h * 128 + w] = s;
    }
  }
}

extern "C" void kernel_launch(void* const* d_in, const int* in_sizes, int n_in,
                              void* d_out, int out_size, void* d_ws, size_t ws_size,
                              hipStream_t stream) {
  const float* gr = (const float*)d_in[0];
  const float* gt = (const float*)d_in[1];
  const float* Wc = (const float*)d_in[2];
  const float* bc = (const float*)d_in[3];
  uint8_t* ws = (uint8_t*)d_ws;
  float* out = (float*)d_out;

  prep_wc<<<162, 256, 0, stream>>>(Wc, ws);
  prep_gt<<<1025, 256, 0, stream>>>(gt, ws);
  dfn_mfma<<<1024, 512, 0, stream>>>(gr, bc, ws, out);
}